// Round 9
// baseline (362.082 us; speedup 1.0000x reference)
//
#include <hip/hip_runtime.h>
#include <hip/hip_bf16.h>
#include <math.h>

#define BB 2
#define TT 2048
#define CC 1024
#define NH 16
#define HD 64
#define BT (BB*TT)          // 4096 rows
#define LN_EPS 1e-5f
#define ATT_SCALE 0.03125f  // C^-0.5 (reference scales by full C, not head_size)

typedef __bf16 bf16x8 __attribute__((ext_vector_type(8)));
typedef __bf16 bf16x4 __attribute__((ext_vector_type(4)));
typedef short shortx4 __attribute__((ext_vector_type(4)));
typedef float floatx4 __attribute__((ext_vector_type(4)));
typedef unsigned int uint32x4 __attribute__((ext_vector_type(4)));
typedef unsigned long long u64;

__device__ __forceinline__ void gl_lds16(const __bf16* g, __bf16* l) {
    __builtin_amdgcn_global_load_lds((const __attribute__((address_space(1))) void*)g,
                                     (__attribute__((address_space(3))) void*)l,
                                     16, 0, 0);
}

// nontemporal helpers (streaming data: don't evict reused tiles from L2)
__device__ __forceinline__ void nt_store64(void* p, u64 v) {
    __builtin_nontemporal_store(v, (u64*)p);
}
__device__ __forceinline__ void nt_store128(void* p, uint32x4 v) {
    __builtin_nontemporal_store(v, (uint32x4*)p);
}
__device__ __forceinline__ u64 nt_load64(const void* p) {
    return __builtin_nontemporal_load((const u64*)p);
}
__device__ __forceinline__ uint32x4 nt_load128(const void* p) {
    return __builtin_nontemporal_load((const uint32x4*)p);
}

#define MFMA32(a, b, c) __builtin_amdgcn_mfma_f32_16x16x32_bf16(a, b, c, 0, 0, 0)

#if __has_builtin(__builtin_amdgcn_mfma_f32_16x16x16_bf16)
__device__ __forceinline__ floatx4 mfma16(bf16x4 a, bf16x4 b, floatx4 c) {
    return __builtin_amdgcn_mfma_f32_16x16x16_bf16(a, b, c, 0, 0, 0);
}
#else
__device__ __forceinline__ floatx4 mfma16(bf16x4 a, bf16x4 b, floatx4 c) {
    return __builtin_amdgcn_mfma_f32_16x16x16bf16_1k(
        __builtin_bit_cast(shortx4, a), __builtin_bit_cast(shortx4, b), c, 0, 0, 0);
}
#endif

// XCD-aware block remap v2. Order index: (x-chunk of 8) outer, then z, then
// y, then x-within-chunk. Each XCD's contiguous 1/8 share covers <=16 y-tiles
// x 8 x-tiles x 1 z-slice -> per-XCD L2 working set <= A 4MB + B 2MB.
__device__ __forceinline__ void swizzle_xcd(int& xb, int& yb, int& zb) {
    const int CW = 8;
    int nx = gridDim.x, ny = gridDim.y, nz = gridDim.z;
    int total = nx * ny * nz;
    int lin = blockIdx.x + nx * (blockIdx.y + ny * blockIdx.z);
    int c = lin & 7, s = lin >> 3;
    int idx = c * (total >> 3) + s;
    int grp = CW * ny * nz;
    int cx = idx / grp, rem = idx % grp;
    zb = rem / (CW * ny);
    int rem2 = rem % (CW * ny);
    yb = rem2 / CW;
    xb = cx * CW + (rem2 & (CW - 1));
}

// ---------------------------------------------------------------------------
// Fused: all weight transposes (idx < 12288) + ln1 (idx >= 12288).
// ---------------------------------------------------------------------------
__global__ __launch_bounds__(256) void transpose_ln(
        const float* __restrict__ Wq, const float* __restrict__ Wk,
        const float* __restrict__ Wv, const float* __restrict__ Wo,
        const float* __restrict__ W1, const float* __restrict__ W2,
        __bf16* __restrict__ WqkvT, __bf16* __restrict__ WoT,
        __bf16* __restrict__ W1T, __bf16* __restrict__ W2T,
        const float* __restrict__ x, const float* __restrict__ g1,
        const float* __restrict__ be1, __bf16* __restrict__ hb) {
    __shared__ float t[32][33];
    __shared__ float rs_[4], rss_[4];
    __shared__ float mu_s, inv_s;
    int idx = blockIdx.x;
    if (idx >= 12288) {
        int row = idx - 12288;
        const float4* xr = (const float4*)(x + (size_t)row * CC);
        float4 v = xr[threadIdx.x];
        float s  = v.x + v.y + v.z + v.w;
        float ss = v.x*v.x + v.y*v.y + v.z*v.z + v.w*v.w;
        #pragma unroll
        for (int off = 32; off; off >>= 1) {
            s  += __shfl_down(s, off);
            ss += __shfl_down(ss, off);
        }
        int lane = threadIdx.x & 63, wid = threadIdx.x >> 6;
        if (lane == 0) { rs_[wid] = s; rss_[wid] = ss; }
        __syncthreads();
        if (threadIdx.x == 0) {
            float S  = rs_[0] + rs_[1] + rs_[2] + rs_[3];
            float SS = rss_[0] + rss_[1] + rss_[2] + rss_[3];
            float mu  = S * (1.0f / CC);
            float var = SS * (1.0f / CC) - mu * mu;
            mu_s  = mu;
            inv_s = rsqrtf(var + LN_EPS);
        }
        __syncthreads();
        float mu = mu_s, inv = inv_s;
        float4 gv = ((const float4*)g1)[threadIdx.x];
        float4 bv = ((const float4*)be1)[threadIdx.x];
        bf16x4 o;
        o[0] = (__bf16)((v.x - mu) * inv * gv.x + bv.x);
        o[1] = (__bf16)((v.y - mu) * inv * gv.y + bv.y);
        o[2] = (__bf16)((v.z - mu) * inv * gv.z + bv.z);
        o[3] = (__bf16)((v.w - mu) * inv * gv.w + bv.w);
        *(bf16x4*)(hb + (size_t)row * CC + threadIdx.x * 4) = o;
        return;
    }
    const float* src; __bf16* dst; int K, N, tn, tk;
    if (idx < 3072) {
        int wsel = idx >> 10, local = idx & 1023;
        src = (wsel == 0) ? Wq : (wsel == 1 ? Wk : Wv);
        dst = WqkvT + (size_t)wsel * 1024 * 1024;
        K = 1024; N = 1024; tn = local & 31; tk = local >> 5;
    } else if (idx < 4096) {
        int local = idx - 3072;
        src = Wo; dst = WoT; K = 1024; N = 1024; tn = local & 31; tk = local >> 5;
    } else if (idx < 8192) {
        int local = idx - 4096;
        src = W1; dst = W1T; K = 1024; N = 4096; tn = local & 127; tk = local >> 7;
    } else {
        int local = idx - 8192;
        src = W2; dst = W2T; K = 4096; N = 1024; tn = local & 31; tk = local >> 5;
    }
    int n0 = tn * 32, k0 = tk * 32;
    int tx = threadIdx.x & 31, ty = threadIdx.x >> 5;
    #pragma unroll
    for (int r = ty; r < 32; r += 8)
        t[r][tx] = src[(size_t)(k0 + r) * N + n0 + tx];
    __syncthreads();
    #pragma unroll
    for (int r = ty; r < 32; r += 8)
        dst[(size_t)(n0 + r) * K + k0 + tx] = (__bf16)t[tx][r];
}

// ---------------------------------------------------------------------------
// Reduce 2 bf16 split-K partials + bias + residual -> x2 (fp32), then LN ->
// hb (bf16). NT loads for streams; NT store for x2.
// ---------------------------------------------------------------------------
__global__ __launch_bounds__(256) void reduce_wo_ln(const __bf16* __restrict__ P,
                                                    const float* __restrict__ bo,
                                                    const float* __restrict__ x,
                                                    const float* __restrict__ g2,
                                                    const float* __restrict__ be2,
                                                    float* __restrict__ x2,
                                                    __bf16* __restrict__ hb) {
    int row = blockIdx.x;
    int c = threadIdx.x * 4;
    bf16x4 a0 = __builtin_bit_cast(bf16x4, nt_load64(P + (size_t)row * CC + c));
    bf16x4 a1 = __builtin_bit_cast(bf16x4, nt_load64(P + (size_t)BT * CC + (size_t)row * CC + c));
    float4 xb = __builtin_bit_cast(float4, nt_load128(x + (size_t)row * CC + c));
    float4 bb = *(const float4*)(bo + c);
    float4 v;
    v.x = xb.x + bb.x + (float)a0[0] + (float)a1[0];
    v.y = xb.y + bb.y + (float)a0[1] + (float)a1[1];
    v.z = xb.z + bb.z + (float)a0[2] + (float)a1[2];
    v.w = xb.w + bb.w + (float)a0[3] + (float)a1[3];
    nt_store128(x2 + (size_t)row * CC + c, __builtin_bit_cast(uint32x4, v));

    float s  = v.x + v.y + v.z + v.w;
    float ss = v.x*v.x + v.y*v.y + v.z*v.z + v.w*v.w;
    #pragma unroll
    for (int off = 32; off; off >>= 1) {
        s  += __shfl_down(s, off);
        ss += __shfl_down(ss, off);
    }
    __shared__ float rs_[4], rss_[4];
    __shared__ float mu_s, inv_s;
    int lane = threadIdx.x & 63, wid = threadIdx.x >> 6;
    if (lane == 0) { rs_[wid] = s; rss_[wid] = ss; }
    __syncthreads();
    if (threadIdx.x == 0) {
        float S  = rs_[0] + rs_[1] + rs_[2] + rs_[3];
        float SS = rss_[0] + rss_[1] + rss_[2] + rss_[3];
        float mu  = S * (1.0f / CC);
        float var = SS * (1.0f / CC) - mu * mu;
        mu_s  = mu;
        inv_s = rsqrtf(var + LN_EPS);
    }
    __syncthreads();
    float mu = mu_s, inv = inv_s;
    float4 gv = ((const float4*)g2)[threadIdx.x];
    float4 bv = ((const float4*)be2)[threadIdx.x];
    bf16x4 o;
    o[0] = (__bf16)((v.x - mu) * inv * gv.x + bv.x);
    o[1] = (__bf16)((v.y - mu) * inv * gv.y + bv.y);
    o[2] = (__bf16)((v.z - mu) * inv * gv.z + bv.z);
    o[3] = (__bf16)((v.w - mu) * inv * gv.w + bv.w);
    *(bf16x4*)(hb + (size_t)row * CC + c) = o;
}

// ---------------------------------------------------------------------------
// Reduce 4 bf16 split-K partials + bias + residual(x2) -> out (fp32).
// ---------------------------------------------------------------------------
__global__ __launch_bounds__(256) void reduce_ffn(const __bf16* __restrict__ P,
                                                  const float* __restrict__ b2,
                                                  const float* __restrict__ x2,
                                                  float* __restrict__ out) {
    int row = blockIdx.x;
    int c = threadIdx.x * 4;
    const size_t S = (size_t)BT * CC;
    float4 v = __builtin_bit_cast(float4, nt_load128(x2 + (size_t)row * CC + c));
    float4 bb = *(const float4*)(b2 + c);
    v.x += bb.x; v.y += bb.y; v.z += bb.z; v.w += bb.w;
    #pragma unroll
    for (int z = 0; z < 4; ++z) {
        bf16x4 a = __builtin_bit_cast(bf16x4, nt_load64(P + z * S + (size_t)row * CC + c));
        v.x += (float)a[0]; v.y += (float)a[1]; v.z += (float)a[2]; v.w += (float)a[3];
    }
    nt_store128(out + (size_t)row * CC + c, __builtin_bit_cast(uint32x4, v));
}

// ---------------------------------------------------------------------------
// bf16 MFMA GEMM v3: C[M,N] = A[M,K] @ Bt[N,K]^T.
// BK=64, XOR-swizzled LDS (round 8), new XCD chunking (swizzle v2), and
// nontemporal stores for all streaming outputs.
// ---------------------------------------------------------------------------
template<int NT, int SK, typename OT, bool BIAS, bool RELU, bool RES, bool VSPLIT>
__global__ __launch_bounds__(256) void gemm_bf16(const __bf16* __restrict__ A,
                                                 const __bf16* __restrict__ Bt,
                                                 const float* __restrict__ bias,
                                                 const float* __restrict__ res,
                                                 OT* __restrict__ C,
                                                 __bf16* __restrict__ vt,
                                                 int M, int N, int K) {
    constexpr int JN = NT / 32;          // 4 or 2
    __shared__ __bf16 As[128 * 64];      // 16 KB
    __shared__ __bf16 Bs[NT * 64];       // 16 or 8 KB
    int bx, by, bz;
    swizzle_xcd(bx, by, bz);
    const int tid = threadIdx.x;
    const int l = tid & 63, w = tid >> 6;
    const int m = l & 15, g = l >> 4;
    const int wm = w >> 1, wn = w & 1;
    const int m0 = by * 128, n0 = bx * NT;
    const int Keff = K / SK;
    const int kbase = (SK > 1) ? bz * Keff : 0;

    const int srow = l >> 3;
    const int sko  = ((l & 7) ^ ((l >> 3) & 7)) * 8;

    floatx4 acc[4][JN];
    #pragma unroll
    for (int i = 0; i < 4; ++i)
        #pragma unroll
        for (int j = 0; j < JN; ++j) {
            floatx4 z = {0.f, 0.f, 0.f, 0.f};
            acc[i][j] = z;
        }

    for (int kt = 0; kt < Keff; kt += 64) {
        __syncthreads();
        #pragma unroll
        for (int c = 0; c < 4; ++c) {
            int idx = w * 4 + c;
            gl_lds16(A + (size_t)(m0 + idx * 8 + srow) * K + kbase + kt + sko,
                     As + idx * 512);
        }
        #pragma unroll
        for (int c = 0; c < JN; ++c) {
            int idx = w * JN + c;
            gl_lds16(Bt + (size_t)(n0 + idx * 8 + srow) * K + kbase + kt + sko,
                     Bs + idx * 512);
        }
        __syncthreads();

        #pragma unroll
        for (int hf = 0; hf < 2; ++hf) {
            const int co = (((hf * 4 + g) ^ (m & 7)) * 8);
            bf16x8 af[4], bfr[JN];
            #pragma unroll
            for (int i = 0; i < 4; ++i)
                af[i] = *(const bf16x8*)&As[(wm * 64 + i * 16 + m) * 64 + co];
            #pragma unroll
            for (int j = 0; j < JN; ++j)
                bfr[j] = *(const bf16x8*)&Bs[(wn * (NT / 2) + j * 16 + m) * 64 + co];
            #pragma unroll
            for (int i = 0; i < 4; ++i)
                #pragma unroll
                for (int j = 0; j < JN; ++j)
                    acc[i][j] = MFMA32(af[i], bfr[j], acc[i][j]);
        }
    }

    if (SK > 1) {
        __bf16* P = (__bf16*)C + (size_t)bz * M * N;
        #pragma unroll
        for (int i = 0; i < 4; ++i) {
            int row = m0 + wm * 64 + i * 16 + g * 4;
            #pragma unroll
            for (int j = 0; j < JN; ++j) {
                int col = n0 + wn * (NT / 2) + j * 16 + m;
                #pragma unroll
                for (int r = 0; r < 4; ++r)
                    __builtin_nontemporal_store((__bf16)acc[i][j][r],
                        P + (size_t)(row + r) * N + col);
            }
        }
    } else if (VSPLIT && n0 >= 2048) {
        // V columns transposed per-head into vt (cached: reused by attention)
        #pragma unroll
        for (int i = 0; i < 4; ++i) {
            int row = m0 + wm * 64 + i * 16 + g * 4;
            int bb = row >> 11, t0 = row & 2047;
            #pragma unroll
            for (int j = 0; j < JN; ++j) {
                int cv = n0 + wn * (NT / 2) + j * 16 + m - 2048;
                bf16x4 o;
                #pragma unroll
                for (int r = 0; r < 4; ++r) o[r] = (__bf16)acc[i][j][r];
                *(bf16x4*)(vt + ((size_t)(bb * NH + (cv >> 6)) * HD + (cv & 63)) * 2048 + t0) = o;
            }
        }
    } else {
        #pragma unroll
        for (int i = 0; i < 4; ++i) {
            int row = m0 + wm * 64 + i * 16 + g * 4;
            #pragma unroll
            for (int j = 0; j < JN; ++j) {
                int col = n0 + wn * (NT / 2) + j * 16 + m;
                float bv = BIAS ? bias[col] : 0.0f;
                #pragma unroll
                for (int r = 0; r < 4; ++r) {
                    float vo = acc[i][j][r] + bv;
                    if (RELU) vo = fmaxf(vo, 0.0f);
                    if (RES)  vo += res[(size_t)(row + r) * N + col];
                    if (VSPLIT)  // q|k of QKV: cached (reused by attention)
                        C[(size_t)(row + r) * N + col] = (OT)vo;
                    else         // ffb: streaming
                        __builtin_nontemporal_store((OT)vo,
                            C + (size_t)(row + r) * N + col);
                }
            }
        }
    }
}

// ---------------------------------------------------------------------------
// Flash attention v3 (round 7): S^T orientation, makespan pairing,
// XOR-swizzled LDS, max-free softmax. Output store now NT.
// ---------------------------------------------------------------------------
__global__ __launch_bounds__(256, 2) void attn_mfma3(const __bf16* __restrict__ qkv,
                                                     const __bf16* __restrict__ vt,
                                                     __bf16* __restrict__ att) {
    const int lin = blockIdx.x;
    const int half = lin >> 8, pid = lin & 255;
    const int q0 = pid & 7, h = (pid >> 3) & 15, b = pid >> 7;
    const int qt = half ? 15 - q0 : q0;

    const int tid = threadIdx.x;
    const int l = tid & 63, w = tid >> 6;
    const int m = l & 15, g = l >> 4;

    __shared__ __bf16 Ks[2][128][32];
    __shared__ __bf16 Vt3[8][64][16];

    const __bf16* qp = qkv + (size_t)b * TT * 3072 + h * HD;
    const __bf16* kp = qp + 1024;
    const __bf16* vh = vt + (size_t)(b * NH + h) * HD * 2048;

    bf16x8 qb[2][2];
    #pragma unroll
    for (int nt = 0; nt < 2; ++nt) {
        int qrow = qt * 128 + w * 32 + nt * 16 + m;
        qb[nt][0] = *(const bf16x8*)(qp + (size_t)qrow * 3072 + g * 8);
        qb[nt][1] = *(const bf16x8*)(qp + (size_t)qrow * 3072 + 32 + g * 8);
    }

    floatx4 O[2][4];
    float l_s[2] = {0.0f, 0.0f};
    #pragma unroll
    for (int nt = 0; nt < 2; ++nt)
        #pragma unroll
        for (int jd = 0; jd < 4; ++jd) {
            floatx4 z = {0.f, 0.f, 0.f, 0.f};
            O[nt][jd] = z;
        }

    for (int kt = 0; kt <= qt; ++kt) {
        __syncthreads();
        #pragma unroll
        for (int c = 0; c < 4; ++c) {
            int idx = w * 4 + c;
            int dh = idx >> 3, k16 = idx & 7;
            gl_lds16(kp + (size_t)(kt * 128 + k16 * 16 + (l >> 2)) * 3072
                        + dh * 32 + (((l & 3) ^ ((l >> 3) & 3)) * 8),
                     (__bf16*)Ks + dh * 4096 + k16 * 512);
        }
        #pragma unroll
        for (int c = 0; c < 4; ++c) {
            int idx = w * 4 + c;
            int jt = idx >> 1, dhf = idx & 1;
            gl_lds16(vh + (size_t)(dhf * 32 + (l >> 1)) * 2048 + kt * 128
                        + jt * 16 + (((l & 1) ^ ((l >> 3) & 1)) * 8),
                     (__bf16*)Vt3 + jt * 1024 + dhf * 512);
        }
        __syncthreads();

        floatx4 S[2][8];
        #pragma unroll
        for (int jt = 0; jt < 8; ++jt) {
            int co = (g ^ ((m >> 1) & 3)) * 8;
            bf16x8 kf0 = *(const bf16x8*)&Ks[0][jt * 16 + m][co];
            bf16x8 kf1 = *(const bf16x8*)&Ks[1][jt * 16 + m][co];
            #pragma unroll
            for (int nt = 0; nt < 2; ++nt) {
                floatx4 z = {0.f, 0.f, 0.f, 0.f};
                z = MFMA32(kf0, qb[nt][0], z);
                S[nt][jt] = MFMA32(kf1, qb[nt][1], z);
            }
        }

        bf16x4 pv[2][8];
        const bool last = (kt == qt);
        #pragma unroll
        for (int nt = 0; nt < 2; ++nt) {
            if (last) {
                int qr = w * 32 + nt * 16 + m;
                #pragma unroll
                for (int jt = 0; jt < 8; ++jt)
                    #pragma unroll
                    for (int r = 0; r < 4; ++r)
                        if (jt * 16 + g * 4 + r > qr) S[nt][jt][r] = -1e30f;
            }
            float ls = 0.0f;
            #pragma unroll
            for (int jt = 0; jt < 8; ++jt) {
                bf16x4 t;
                #pragma unroll
                for (int r = 0; r < 4; ++r) {
                    float p = __expf(S[nt][jt][r] * ATT_SCALE);
                    ls += p;
                    t[r] = (__bf16)p;
                }
                pv[nt][jt] = t;
            }
            l_s[nt] += ls;
        }

        #pragma unroll
        for (int jt = 0; jt < 8; ++jt)
            #pragma unroll
            for (int jd = 0; jd < 4; ++jd) {
                bf16x4 vf = *(const bf16x4*)&Vt3[jt][jd * 16 + m]
                                [((g >> 1) ^ ((m >> 2) & 1)) * 8 + (g & 1) * 4];
                #pragma unroll
                for (int nt = 0; nt < 2; ++nt)
                    O[nt][jd] = mfma16(vf, pv[nt][jt], O[nt][jd]);
            }
    }

    #pragma unroll
    for (int nt = 0; nt < 2; ++nt) {
        float lsum = l_s[nt];
        lsum += __shfl_xor(lsum, 16, 64);
        lsum += __shfl_xor(lsum, 32, 64);
        float inv = 1.0f / lsum;
        int qrow = qt * 128 + w * 32 + nt * 16 + m;
        #pragma unroll
        for (int jd = 0; jd < 4; ++jd) {
            bf16x4 o;
            #pragma unroll
            for (int r = 0; r < 4; ++r) o[r] = (__bf16)(O[nt][jd][r] * inv);
            nt_store64(att + ((size_t)b * TT + qrow) * CC + h * HD + jd * 16 + g * 4,
                       __builtin_bit_cast(u64, o));
        }
    }
}

// ---------------------------------------------------------------------------
extern "C" void kernel_launch(void* const* d_in, const int* in_sizes, int n_in,
                              void* d_out, int out_size, void* d_ws, size_t ws_size,
                              hipStream_t stream) {
    const float* x   = (const float*)d_in[0];
    const float* Wq  = (const float*)d_in[1];
    const float* Wk  = (const float*)d_in[2];
    const float* Wv  = (const float*)d_in[3];
    const float* Wo  = (const float*)d_in[4];
    const float* bo  = (const float*)d_in[5];
    const float* W1  = (const float*)d_in[6];
    const float* b1  = (const float*)d_in[7];
    const float* W2  = (const float*)d_in[8];
    const float* b2  = (const float*)d_in[9];
    const float* g1  = (const float*)d_in[10];
    const float* be1 = (const float*)d_in[11];
    const float* g2  = (const float*)d_in[12];
    const float* be2 = (const float*)d_in[13];
    float* out = (float*)d_out;

    char* p = (char*)d_ws;
    char*   pool  = p;          p += (size_t)32 * 1024 * 1024;
    __bf16* qkvb  = (__bf16*)pool;
    __bf16* vtb   = (__bf16*)(pool + (size_t)BT * 3072 * 2);
    __bf16* wop   = (__bf16*)pool;     // 2 x [BT][CC] bf16 partials
    __bf16* ffp   = (__bf16*)pool;     // 4 x [BT][CC] bf16 partials
    __bf16* attb  = (__bf16*)p; p += (size_t)BT * CC * 2;
    __bf16* hb    = (__bf16*)p; p += (size_t)BT * CC * 2;
    float*  x2    = (float*)p;  p += (size_t)BT * CC * 4;
    __bf16* ffb   = (__bf16*)p; p += (size_t)BT * 4096 * 2;
    __bf16* WqkvT = (__bf16*)p; p += (size_t)3072 * 1024 * 2;
    __bf16* WoT   = (__bf16*)p; p += (size_t)1024 * 1024 * 2;
    __bf16* W1T   = (__bf16*)p; p += (size_t)4096 * 1024 * 2;
    __bf16* W2T   = (__bf16*)p; p += (size_t)1024 * 4096 * 2;

    transpose_ln<<<16384, 256, 0, stream>>>(Wq, Wk, Wv, Wo, W1, W2,
                                            WqkvT, WoT, W1T, W2T,
                                            x, g1, be1, hb);
    // fused QKV projection; V written transposed into vtb
    gemm_bf16<128, 1, __bf16, false, false, false, true><<<dim3(24, 32), 256, 0, stream>>>(
        hb, WqkvT, nullptr, nullptr, qkvb, vtb, BT, 3072, 1024);
    attn_mfma3<<<512, 256, 0, stream>>>(qkvb, vtb, attb);
    // out proj: split-K=2 bf16 partials (NT-stored)
    gemm_bf16<64, 2, __bf16, false, false, false, false><<<dim3(16, 32, 2), 256, 0, stream>>>(
        attb, WoT, nullptr, nullptr, wop, nullptr, BT, 1024, 1024);
    reduce_wo_ln<<<BT, 256, 0, stream>>>(wop, bo, x, g2, be2, x2, hb);
    // ffn1 + bias + relu (ffb NT-stored)
    gemm_bf16<128, 1, __bf16, true, true, false, false><<<dim3(32, 32), 256, 0, stream>>>(
        hb, W1T, b1, nullptr, ffb, nullptr, BT, 4096, 1024);
    // ffn2: split-K=4 bf16 partials (NT-stored)
    gemm_bf16<128, 4, __bf16, false, false, false, false><<<dim3(8, 32, 4), 256, 0, stream>>>(
        ffb, W2T, nullptr, nullptr, ffp, nullptr, BT, 1024, 4096);
    reduce_ffn<<<BT, 256, 0, stream>>>(ffp, b2, x2, out);
}

// Round 10
// 349.203 us; speedup vs baseline: 1.0369x; 1.0369x over previous
//
#include <hip/hip_runtime.h>
#include <hip/hip_bf16.h>
#include <math.h>

#define BB 2
#define TT 2048
#define CC 1024
#define NH 16
#define HD 64
#define BT (BB*TT)          // 4096 rows
#define LN_EPS 1e-5f
#define ATT_SCALE 0.03125f  // C^-0.5 (reference scales by full C, not head_size)

typedef __bf16 bf16x8 __attribute__((ext_vector_type(8)));
typedef __bf16 bf16x4 __attribute__((ext_vector_type(4)));
typedef short shortx4 __attribute__((ext_vector_type(4)));
typedef float floatx4 __attribute__((ext_vector_type(4)));
typedef unsigned int uint32x4 __attribute__((ext_vector_type(4)));
typedef unsigned long long u64;

__device__ __forceinline__ void gl_lds16(const __bf16* g, __bf16* l) {
    __builtin_amdgcn_global_load_lds((const __attribute__((address_space(1))) void*)g,
                                     (__attribute__((address_space(3))) void*)l,
                                     16, 0, 0);
}

__device__ __forceinline__ u64 nt_load64(const void* p) {
    return __builtin_nontemporal_load((const u64*)p);
}
__device__ __forceinline__ uint32x4 nt_load128(const void* p) {
    return __builtin_nontemporal_load((const uint32x4*)p);
}
__device__ __forceinline__ void nt_store128(void* p, uint32x4 v) {
    __builtin_nontemporal_store(v, (uint32x4*)p);
}

#define MFMA32(a, b, c) __builtin_amdgcn_mfma_f32_16x16x32_bf16(a, b, c, 0, 0, 0)

#if __has_builtin(__builtin_amdgcn_mfma_f32_16x16x16_bf16)
__device__ __forceinline__ floatx4 mfma16(bf16x4 a, bf16x4 b, floatx4 c) {
    return __builtin_amdgcn_mfma_f32_16x16x16_bf16(a, b, c, 0, 0, 0);
}
#else
__device__ __forceinline__ floatx4 mfma16(bf16x4 a, bf16x4 b, floatx4 c) {
    return __builtin_amdgcn_mfma_f32_16x16x16bf16_1k(
        __builtin_bit_cast(shortx4, a), __builtin_bit_cast(shortx4, b), c, 0, 0, 0);
}
#endif

// XCD-aware block remap (round 9): contiguous 1/8 shares with 8-wide x-chunks,
// z innermost -> per-XCD L2 working set <= A 4MB + B 2MB.
__device__ __forceinline__ void swizzle_xcd(int& xb, int& yb, int& zb) {
    const int CW = 8;
    int nx = gridDim.x, ny = gridDim.y, nz = gridDim.z;
    int total = nx * ny * nz;
    int lin = blockIdx.x + nx * (blockIdx.y + ny * blockIdx.z);
    int c = lin & 7, s = lin >> 3;
    int idx = c * (total >> 3) + s;
    int grp = CW * ny * nz;
    int cx = idx / grp, rem = idx % grp;
    zb = rem / (CW * ny);
    int rem2 = rem % (CW * ny);
    yb = rem2 / CW;
    xb = cx * CW + (rem2 & (CW - 1));
}

// ---------------------------------------------------------------------------
// Fused: all weight transposes (idx < 12288) + ln1 (idx >= 12288).
// ---------------------------------------------------------------------------
__global__ __launch_bounds__(256) void transpose_ln(
        const float* __restrict__ Wq, const float* __restrict__ Wk,
        const float* __restrict__ Wv, const float* __restrict__ Wo,
        const float* __restrict__ W1, const float* __restrict__ W2,
        __bf16* __restrict__ WqkvT, __bf16* __restrict__ WoT,
        __bf16* __restrict__ W1T, __bf16* __restrict__ W2T,
        const float* __restrict__ x, const float* __restrict__ g1,
        const float* __restrict__ be1, __bf16* __restrict__ hb) {
    __shared__ float t[32][33];
    __shared__ float rs_[4], rss_[4];
    __shared__ float mu_s, inv_s;
    int idx = blockIdx.x;
    if (idx >= 12288) {
        int row = idx - 12288;
        const float4* xr = (const float4*)(x + (size_t)row * CC);
        float4 v = xr[threadIdx.x];
        float s  = v.x + v.y + v.z + v.w;
        float ss = v.x*v.x + v.y*v.y + v.z*v.z + v.w*v.w;
        #pragma unroll
        for (int off = 32; off; off >>= 1) {
            s  += __shfl_down(s, off);
            ss += __shfl_down(ss, off);
        }
        int lane = threadIdx.x & 63, wid = threadIdx.x >> 6;
        if (lane == 0) { rs_[wid] = s; rss_[wid] = ss; }
        __syncthreads();
        if (threadIdx.x == 0) {
            float S  = rs_[0] + rs_[1] + rs_[2] + rs_[3];
            float SS = rss_[0] + rss_[1] + rss_[2] + rss_[3];
            float mu  = S * (1.0f / CC);
            float var = SS * (1.0f / CC) - mu * mu;
            mu_s  = mu;
            inv_s = rsqrtf(var + LN_EPS);
        }
        __syncthreads();
        float mu = mu_s, inv = inv_s;
        float4 gv = ((const float4*)g1)[threadIdx.x];
        float4 bv = ((const float4*)be1)[threadIdx.x];
        bf16x4 o;
        o[0] = (__bf16)((v.x - mu) * inv * gv.x + bv.x);
        o[1] = (__bf16)((v.y - mu) * inv * gv.y + bv.y);
        o[2] = (__bf16)((v.z - mu) * inv * gv.z + bv.z);
        o[3] = (__bf16)((v.w - mu) * inv * gv.w + bv.w);
        *(bf16x4*)(hb + (size_t)row * CC + threadIdx.x * 4) = o;
        return;
    }
    const float* src; __bf16* dst; int K, N, tn, tk;
    if (idx < 3072) {
        int wsel = idx >> 10, local = idx & 1023;
        src = (wsel == 0) ? Wq : (wsel == 1 ? Wk : Wv);
        dst = WqkvT + (size_t)wsel * 1024 * 1024;
        K = 1024; N = 1024; tn = local & 31; tk = local >> 5;
    } else if (idx < 4096) {
        int local = idx - 3072;
        src = Wo; dst = WoT; K = 1024; N = 1024; tn = local & 31; tk = local >> 5;
    } else if (idx < 8192) {
        int local = idx - 4096;
        src = W1; dst = W1T; K = 1024; N = 4096; tn = local & 127; tk = local >> 7;
    } else {
        int local = idx - 8192;
        src = W2; dst = W2T; K = 4096; N = 1024; tn = local & 31; tk = local >> 5;
    }
    int n0 = tn * 32, k0 = tk * 32;
    int tx = threadIdx.x & 31, ty = threadIdx.x >> 5;
    #pragma unroll
    for (int r = ty; r < 32; r += 8)
        t[r][tx] = src[(size_t)(k0 + r) * N + n0 + tx];
    __syncthreads();
    #pragma unroll
    for (int r = ty; r < 32; r += 8)
        dst[(size_t)(n0 + r) * K + k0 + tx] = (__bf16)t[tx][r];
}

// ---------------------------------------------------------------------------
// Reduce 2 bf16 split-K partials + bias + residual -> x2 (fp32), then LN ->
// hb (bf16). NT loads for streams; NT store for x2 (16B coalesced).
// ---------------------------------------------------------------------------
__global__ __launch_bounds__(256) void reduce_wo_ln(const __bf16* __restrict__ P,
                                                    const float* __restrict__ bo,
                                                    const float* __restrict__ x,
                                                    const float* __restrict__ g2,
                                                    const float* __restrict__ be2,
                                                    float* __restrict__ x2,
                                                    __bf16* __restrict__ hb) {
    int row = blockIdx.x;
    int c = threadIdx.x * 4;
    bf16x4 a0 = __builtin_bit_cast(bf16x4, nt_load64(P + (size_t)row * CC + c));
    bf16x4 a1 = __builtin_bit_cast(bf16x4, nt_load64(P + (size_t)BT * CC + (size_t)row * CC + c));
    float4 xb = __builtin_bit_cast(float4, nt_load128(x + (size_t)row * CC + c));
    float4 bb = *(const float4*)(bo + c);
    float4 v;
    v.x = xb.x + bb.x + (float)a0[0] + (float)a1[0];
    v.y = xb.y + bb.y + (float)a0[1] + (float)a1[1];
    v.z = xb.z + bb.z + (float)a0[2] + (float)a1[2];
    v.w = xb.w + bb.w + (float)a0[3] + (float)a1[3];
    nt_store128(x2 + (size_t)row * CC + c, __builtin_bit_cast(uint32x4, v));

    float s  = v.x + v.y + v.z + v.w;
    float ss = v.x*v.x + v.y*v.y + v.z*v.z + v.w*v.w;
    #pragma unroll
    for (int off = 32; off; off >>= 1) {
        s  += __shfl_down(s, off);
        ss += __shfl_down(ss, off);
    }
    __shared__ float rs_[4], rss_[4];
    __shared__ float mu_s, inv_s;
    int lane = threadIdx.x & 63, wid = threadIdx.x >> 6;
    if (lane == 0) { rs_[wid] = s; rss_[wid] = ss; }
    __syncthreads();
    if (threadIdx.x == 0) {
        float S  = rs_[0] + rs_[1] + rs_[2] + rs_[3];
        float SS = rss_[0] + rss_[1] + rss_[2] + rss_[3];
        float mu  = S * (1.0f / CC);
        float var = SS * (1.0f / CC) - mu * mu;
        mu_s  = mu;
        inv_s = rsqrtf(var + LN_EPS);
    }
    __syncthreads();
    float mu = mu_s, inv = inv_s;
    float4 gv = ((const float4*)g2)[threadIdx.x];
    float4 bv = ((const float4*)be2)[threadIdx.x];
    bf16x4 o;
    o[0] = (__bf16)((v.x - mu) * inv * gv.x + bv.x);
    o[1] = (__bf16)((v.y - mu) * inv * gv.y + bv.y);
    o[2] = (__bf16)((v.z - mu) * inv * gv.z + bv.z);
    o[3] = (__bf16)((v.w - mu) * inv * gv.w + bv.w);
    *(bf16x4*)(hb + (size_t)row * CC + c) = o;
}

// ---------------------------------------------------------------------------
// Reduce 4 bf16 split-K partials + bias + residual(x2) -> out (fp32).
// ---------------------------------------------------------------------------
__global__ __launch_bounds__(256) void reduce_ffn(const __bf16* __restrict__ P,
                                                  const float* __restrict__ b2,
                                                  const float* __restrict__ x2,
                                                  float* __restrict__ out) {
    int row = blockIdx.x;
    int c = threadIdx.x * 4;
    const size_t S = (size_t)BT * CC;
    float4 v = __builtin_bit_cast(float4, nt_load128(x2 + (size_t)row * CC + c));
    float4 bb = *(const float4*)(b2 + c);
    v.x += bb.x; v.y += bb.y; v.z += bb.z; v.w += bb.w;
    #pragma unroll
    for (int z = 0; z < 4; ++z) {
        bf16x4 a = __builtin_bit_cast(bf16x4, nt_load64(P + z * S + (size_t)row * CC + c));
        v.x += (float)a[0]; v.y += (float)a[1]; v.z += (float)a[2]; v.w += (float)a[3];
    }
    nt_store128(out + (size_t)row * CC + c, __builtin_bit_cast(uint32x4, v));
}

// ---------------------------------------------------------------------------
// bf16 MFMA GEMM v4: C[M,N] = A[M,K] @ Bt[N,K]^T.
// BK=64, XOR-swizzled LDS loads (r8), XCD chunking (r9). Round-10: streaming
// bf16 outputs (split-K partials, STREAMC) are staged through LDS (reusing
// the As/Bs space after the K loop, XOR chunk swizzle) and written with
// fully-coalesced 16B nontemporal stores — fixes r9's partial-line NT writes.
// ---------------------------------------------------------------------------
template<int NT, int SK, typename OT, bool BIAS, bool RELU, bool RES,
         bool VSPLIT, bool STREAMC>
__global__ __launch_bounds__(256) void gemm_bf16(const __bf16* __restrict__ A,
                                                 const __bf16* __restrict__ Bt,
                                                 const float* __restrict__ bias,
                                                 const float* __restrict__ res,
                                                 OT* __restrict__ C,
                                                 __bf16* __restrict__ vt,
                                                 int M, int N, int K) {
    constexpr int JN = NT / 32;          // 4 or 2
    __shared__ __bf16 smem[128 * 64 + NT * 64];
    __bf16* As = smem;
    __bf16* Bs = smem + 128 * 64;
    int bx, by, bz;
    swizzle_xcd(bx, by, bz);
    const int tid = threadIdx.x;
    const int l = tid & 63, w = tid >> 6;
    const int m = l & 15, g = l >> 4;
    const int wm = w >> 1, wn = w & 1;
    const int m0 = by * 128, n0 = bx * NT;
    const int Keff = K / SK;
    const int kbase = (SK > 1) ? bz * Keff : 0;

    const int srow = l >> 3;
    const int sko  = ((l & 7) ^ ((l >> 3) & 7)) * 8;

    floatx4 acc[4][JN];
    #pragma unroll
    for (int i = 0; i < 4; ++i)
        #pragma unroll
        for (int j = 0; j < JN; ++j) {
            floatx4 z = {0.f, 0.f, 0.f, 0.f};
            acc[i][j] = z;
        }

    for (int kt = 0; kt < Keff; kt += 64) {
        __syncthreads();
        #pragma unroll
        for (int c = 0; c < 4; ++c) {
            int idx = w * 4 + c;
            gl_lds16(A + (size_t)(m0 + idx * 8 + srow) * K + kbase + kt + sko,
                     As + idx * 512);
        }
        #pragma unroll
        for (int c = 0; c < JN; ++c) {
            int idx = w * JN + c;
            gl_lds16(Bt + (size_t)(n0 + idx * 8 + srow) * K + kbase + kt + sko,
                     Bs + idx * 512);
        }
        __syncthreads();

        #pragma unroll
        for (int hf = 0; hf < 2; ++hf) {
            const int co = (((hf * 4 + g) ^ (m & 7)) * 8);
            bf16x8 af[4], bfr[JN];
            #pragma unroll
            for (int i = 0; i < 4; ++i)
                af[i] = *(const bf16x8*)&As[(wm * 64 + i * 16 + m) * 64 + co];
            #pragma unroll
            for (int j = 0; j < JN; ++j)
                bfr[j] = *(const bf16x8*)&Bs[(wn * (NT / 2) + j * 16 + m) * 64 + co];
            #pragma unroll
            for (int i = 0; i < 4; ++i)
                #pragma unroll
                for (int j = 0; j < JN; ++j)
                    acc[i][j] = MFMA32(af[i], bfr[j], acc[i][j]);
        }
    }

    if (SK > 1 || STREAMC) {
        // ---- LDS-staged coalesced NT epilogue (streaming bf16 output) ----
        constexpr int CPR = NT / 8;     // 16B chunks per row
        __syncthreads();                // MFMA frag reads done; reuse smem
        #pragma unroll
        for (int i = 0; i < 4; ++i) {
            int lr0 = wm * 64 + i * 16 + g * 4;
            #pragma unroll
            for (int j = 0; j < JN; ++j) {
                int lcol = wn * (NT / 2) + j * 16 + m;
                int chunk = lcol >> 3, off = lcol & 7;
                float bv = BIAS ? bias[n0 + lcol] : 0.0f;
                #pragma unroll
                for (int r = 0; r < 4; ++r) {
                    float vo = acc[i][j][r] + bv;
                    if (RELU) vo = fmaxf(vo, 0.0f);
                    int lrow = lr0 + r;
                    smem[lrow * NT + ((chunk ^ (lrow & (CPR - 1))) * 8) + off] = (__bf16)vo;
                }
            }
        }
        __syncthreads();
        __bf16* base = (SK > 1) ? (__bf16*)C + (size_t)bz * M * N : (__bf16*)C;
        const int rpp = 256 / CPR;      // rows per pass
        #pragma unroll
        for (int ps = 0; ps < 128 / rpp; ++ps) {
            int lrow = ps * rpp + tid / CPR;
            int chunk = tid % CPR;
            int phys = chunk ^ (lrow & (CPR - 1));
            bf16x8 v = *(const bf16x8*)&smem[lrow * NT + phys * 8];
            __builtin_nontemporal_store(__builtin_bit_cast(uint32x4, v),
                (uint32x4*)(base + (size_t)(m0 + lrow) * N + n0 + chunk * 8));
        }
    } else if (VSPLIT && n0 >= 2048) {
        // V columns transposed per-head into vt (cached: reused by attention)
        #pragma unroll
        for (int i = 0; i < 4; ++i) {
            int row = m0 + wm * 64 + i * 16 + g * 4;
            int bb = row >> 11, t0 = row & 2047;
            #pragma unroll
            for (int j = 0; j < JN; ++j) {
                int cv = n0 + wn * (NT / 2) + j * 16 + m - 2048;
                bf16x4 o;
                #pragma unroll
                for (int r = 0; r < 4; ++r) o[r] = (__bf16)acc[i][j][r];
                *(bf16x4*)(vt + ((size_t)(bb * NH + (cv >> 6)) * HD + (cv & 63)) * 2048 + t0) = o;
            }
        }
    } else {
        // cached epilogue (q|k of QKV, or fp32 outputs)
        #pragma unroll
        for (int i = 0; i < 4; ++i) {
            int row = m0 + wm * 64 + i * 16 + g * 4;
            #pragma unroll
            for (int j = 0; j < JN; ++j) {
                int col = n0 + wn * (NT / 2) + j * 16 + m;
                float bv = BIAS ? bias[col] : 0.0f;
                #pragma unroll
                for (int r = 0; r < 4; ++r) {
                    float vo = acc[i][j][r] + bv;
                    if (RELU) vo = fmaxf(vo, 0.0f);
                    if (RES)  vo += res[(size_t)(row + r) * N + col];
                    C[(size_t)(row + r) * N + col] = (OT)vo;
                }
            }
        }
    }
}

// ---------------------------------------------------------------------------
// Flash attention v3 (round 7): S^T orientation, makespan pairing,
// XOR-swizzled LDS, max-free softmax. Cached output store (read by Wo GEMM).
// ---------------------------------------------------------------------------
__global__ __launch_bounds__(256, 2) void attn_mfma3(const __bf16* __restrict__ qkv,
                                                     const __bf16* __restrict__ vt,
                                                     __bf16* __restrict__ att) {
    const int lin = blockIdx.x;
    const int half = lin >> 8, pid = lin & 255;
    const int q0 = pid & 7, h = (pid >> 3) & 15, b = pid >> 7;
    const int qt = half ? 15 - q0 : q0;

    const int tid = threadIdx.x;
    const int l = tid & 63, w = tid >> 6;
    const int m = l & 15, g = l >> 4;

    __shared__ __bf16 Ks[2][128][32];
    __shared__ __bf16 Vt3[8][64][16];

    const __bf16* qp = qkv + (size_t)b * TT * 3072 + h * HD;
    const __bf16* kp = qp + 1024;
    const __bf16* vh = vt + (size_t)(b * NH + h) * HD * 2048;

    bf16x8 qb[2][2];
    #pragma unroll
    for (int nt = 0; nt < 2; ++nt) {
        int qrow = qt * 128 + w * 32 + nt * 16 + m;
        qb[nt][0] = *(const bf16x8*)(qp + (size_t)qrow * 3072 + g * 8);
        qb[nt][1] = *(const bf16x8*)(qp + (size_t)qrow * 3072 + 32 + g * 8);
    }

    floatx4 O[2][4];
    float l_s[2] = {0.0f, 0.0f};
    #pragma unroll
    for (int nt = 0; nt < 2; ++nt)
        #pragma unroll
        for (int jd = 0; jd < 4; ++jd) {
            floatx4 z = {0.f, 0.f, 0.f, 0.f};
            O[nt][jd] = z;
        }

    for (int kt = 0; kt <= qt; ++kt) {
        __syncthreads();
        #pragma unroll
        for (int c = 0; c < 4; ++c) {
            int idx = w * 4 + c;
            int dh = idx >> 3, k16 = idx & 7;
            gl_lds16(kp + (size_t)(kt * 128 + k16 * 16 + (l >> 2)) * 3072
                        + dh * 32 + (((l & 3) ^ ((l >> 3) & 3)) * 8),
                     (__bf16*)Ks + dh * 4096 + k16 * 512);
        }
        #pragma unroll
        for (int c = 0; c < 4; ++c) {
            int idx = w * 4 + c;
            int jt = idx >> 1, dhf = idx & 1;
            gl_lds16(vh + (size_t)(dhf * 32 + (l >> 1)) * 2048 + kt * 128
                        + jt * 16 + (((l & 1) ^ ((l >> 3) & 1)) * 8),
                     (__bf16*)Vt3 + jt * 1024 + dhf * 512);
        }
        __syncthreads();

        floatx4 S[2][8];
        #pragma unroll
        for (int jt = 0; jt < 8; ++jt) {
            int co = (g ^ ((m >> 1) & 3)) * 8;
            bf16x8 kf0 = *(const bf16x8*)&Ks[0][jt * 16 + m][co];
            bf16x8 kf1 = *(const bf16x8*)&Ks[1][jt * 16 + m][co];
            #pragma unroll
            for (int nt = 0; nt < 2; ++nt) {
                floatx4 z = {0.f, 0.f, 0.f, 0.f};
                z = MFMA32(kf0, qb[nt][0], z);
                S[nt][jt] = MFMA32(kf1, qb[nt][1], z);
            }
        }

        bf16x4 pv[2][8];
        const bool last = (kt == qt);
        #pragma unroll
        for (int nt = 0; nt < 2; ++nt) {
            if (last) {
                int qr = w * 32 + nt * 16 + m;
                #pragma unroll
                for (int jt = 0; jt < 8; ++jt)
                    #pragma unroll
                    for (int r = 0; r < 4; ++r)
                        if (jt * 16 + g * 4 + r > qr) S[nt][jt][r] = -1e30f;
            }
            float ls = 0.0f;
            #pragma unroll
            for (int jt = 0; jt < 8; ++jt) {
                bf16x4 t;
                #pragma unroll
                for (int r = 0; r < 4; ++r) {
                    float p = __expf(S[nt][jt][r] * ATT_SCALE);
                    ls += p;
                    t[r] = (__bf16)p;
                }
                pv[nt][jt] = t;
            }
            l_s[nt] += ls;
        }

        #pragma unroll
        for (int jt = 0; jt < 8; ++jt)
            #pragma unroll
            for (int jd = 0; jd < 4; ++jd) {
                bf16x4 vf = *(const bf16x4*)&Vt3[jt][jd * 16 + m]
                                [((g >> 1) ^ ((m >> 2) & 1)) * 8 + (g & 1) * 4];
                #pragma unroll
                for (int nt = 0; nt < 2; ++nt)
                    O[nt][jd] = mfma16(vf, pv[nt][jt], O[nt][jd]);
            }
    }

    #pragma unroll
    for (int nt = 0; nt < 2; ++nt) {
        float lsum = l_s[nt];
        lsum += __shfl_xor(lsum, 16, 64);
        lsum += __shfl_xor(lsum, 32, 64);
        float inv = 1.0f / lsum;
        int qrow = qt * 128 + w * 32 + nt * 16 + m;
        #pragma unroll
        for (int jd = 0; jd < 4; ++jd) {
            bf16x4 o;
            #pragma unroll
            for (int r = 0; r < 4; ++r) o[r] = (__bf16)(O[nt][jd][r] * inv);
            *(bf16x4*)(att + ((size_t)b * TT + qrow) * CC + h * HD + jd * 16 + g * 4) = o;
        }
    }
}

// ---------------------------------------------------------------------------
extern "C" void kernel_launch(void* const* d_in, const int* in_sizes, int n_in,
                              void* d_out, int out_size, void* d_ws, size_t ws_size,
                              hipStream_t stream) {
    const float* x   = (const float*)d_in[0];
    const float* Wq  = (const float*)d_in[1];
    const float* Wk  = (const float*)d_in[2];
    const float* Wv  = (const float*)d_in[3];
    const float* Wo  = (const float*)d_in[4];
    const float* bo  = (const float*)d_in[5];
    const float* W1  = (const float*)d_in[6];
    const float* b1  = (const float*)d_in[7];
    const float* W2  = (const float*)d_in[8];
    const float* b2  = (const float*)d_in[9];
    const float* g1  = (const float*)d_in[10];
    const float* be1 = (const float*)d_in[11];
    const float* g2  = (const float*)d_in[12];
    const float* be2 = (const float*)d_in[13];
    float* out = (float*)d_out;

    char* p = (char*)d_ws;
    char*   pool  = p;          p += (size_t)32 * 1024 * 1024;
    __bf16* qkvb  = (__bf16*)pool;
    __bf16* vtb   = (__bf16*)(pool + (size_t)BT * 3072 * 2);
    __bf16* wop   = (__bf16*)pool;     // 2 x [BT][CC] bf16 partials
    __bf16* ffp   = (__bf16*)pool;     // 4 x [BT][CC] bf16 partials
    __bf16* attb  = (__bf16*)p; p += (size_t)BT * CC * 2;
    __bf16* hb    = (__bf16*)p; p += (size_t)BT * CC * 2;
    float*  x2    = (float*)p;  p += (size_t)BT * CC * 4;
    __bf16* ffb   = (__bf16*)p; p += (size_t)BT * 4096 * 2;
    __bf16* WqkvT = (__bf16*)p; p += (size_t)3072 * 1024 * 2;
    __bf16* WoT   = (__bf16*)p; p += (size_t)1024 * 1024 * 2;
    __bf16* W1T   = (__bf16*)p; p += (size_t)4096 * 1024 * 2;
    __bf16* W2T   = (__bf16*)p; p += (size_t)1024 * 4096 * 2;

    transpose_ln<<<16384, 256, 0, stream>>>(Wq, Wk, Wv, Wo, W1, W2,
                                            WqkvT, WoT, W1T, W2T,
                                            x, g1, be1, hb);
    // fused QKV projection; V written transposed into vtb (cached stores)
    gemm_bf16<128, 1, __bf16, false, false, false, true, false><<<dim3(24, 32), 256, 0, stream>>>(
        hb, WqkvT, nullptr, nullptr, qkvb, vtb, BT, 3072, 1024);
    attn_mfma3<<<512, 256, 0, stream>>>(qkvb, vtb, attb);
    // out proj: split-K=2 partials, LDS-staged coalesced NT stores
    gemm_bf16<64, 2, __bf16, false, false, false, false, false><<<dim3(16, 32, 2), 256, 0, stream>>>(
        attb, WoT, nullptr, nullptr, wop, nullptr, BT, 1024, 1024);
    reduce_wo_ln<<<BT, 256, 0, stream>>>(wop, bo, x, g2, be2, x2, hb);
    // ffn1 + bias + relu -> ffb, LDS-staged coalesced NT stores
    gemm_bf16<128, 1, __bf16, true, true, false, false, true><<<dim3(32, 32), 256, 0, stream>>>(
        hb, W1T, b1, nullptr, ffb, nullptr, BT, 4096, 1024);
    // ffn2: split-K=4 partials, LDS-staged coalesced NT stores
    gemm_bf16<128, 4, __bf16, false, false, false, false, false><<<dim3(8, 32, 4), 256, 0, stream>>>(
        ffb, W2T, nullptr, nullptr, ffp, nullptr, BT, 1024, 4096);
    reduce_ffn<<<BT, 256, 0, stream>>>(ffp, b2, x2, out);
}

// Round 11
// 344.310 us; speedup vs baseline: 1.0516x; 1.0142x over previous
//
#include <hip/hip_runtime.h>
#include <hip/hip_bf16.h>
#include <math.h>

#define BB 2
#define TT 2048
#define CC 1024
#define NH 16
#define HD 64
#define BT (BB*TT)          // 4096 rows
#define LN_EPS 1e-5f
#define ATT_SCALE 0.03125f  // C^-0.5 (reference scales by full C, not head_size)

typedef __bf16 bf16x8 __attribute__((ext_vector_type(8)));
typedef __bf16 bf16x4 __attribute__((ext_vector_type(4)));
typedef short shortx4 __attribute__((ext_vector_type(4)));
typedef float floatx4 __attribute__((ext_vector_type(4)));
typedef unsigned int uint32x4 __attribute__((ext_vector_type(4)));
typedef unsigned long long u64;

__device__ __forceinline__ void gl_lds16(const __bf16* g, __bf16* l) {
    __builtin_amdgcn_global_load_lds((const __attribute__((address_space(1))) void*)g,
                                     (__attribute__((address_space(3))) void*)l,
                                     16, 0, 0);
}

__device__ __forceinline__ uint32x4 nt_load128(const void* p) {
    return __builtin_nontemporal_load((const uint32x4*)p);
}
__device__ __forceinline__ void nt_store128(void* p, uint32x4 v) {
    __builtin_nontemporal_store(v, (uint32x4*)p);
}

#define MFMA32(a, b, c) __builtin_amdgcn_mfma_f32_16x16x32_bf16(a, b, c, 0, 0, 0)

#if __has_builtin(__builtin_amdgcn_mfma_f32_16x16x16_bf16)
__device__ __forceinline__ floatx4 mfma16(bf16x4 a, bf16x4 b, floatx4 c) {
    return __builtin_amdgcn_mfma_f32_16x16x16_bf16(a, b, c, 0, 0, 0);
}
#else
__device__ __forceinline__ floatx4 mfma16(bf16x4 a, bf16x4 b, floatx4 c) {
    return __builtin_amdgcn_mfma_f32_16x16x16bf16_1k(
        __builtin_bit_cast(shortx4, a), __builtin_bit_cast(shortx4, b), c, 0, 0, 0);
}
#endif

// XCD-aware block remap: contiguous 1/8 shares with 8-wide x-chunks,
// z outer -> per-XCD L2 working set <= A 4MB + B 2MB.
__device__ __forceinline__ void swizzle_xcd(int& xb, int& yb, int& zb) {
    const int CW = 8;
    int nx = gridDim.x, ny = gridDim.y, nz = gridDim.z;
    int total = nx * ny * nz;
    int lin = blockIdx.x + nx * (blockIdx.y + ny * blockIdx.z);
    int c = lin & 7, s = lin >> 3;
    int idx = c * (total >> 3) + s;
    int grp = CW * ny * nz;
    int cx = idx / grp, rem = idx % grp;
    zb = rem / (CW * ny);
    int rem2 = rem % (CW * ny);
    yb = rem2 / CW;
    xb = cx * CW + (rem2 & (CW - 1));
}

// ---------------------------------------------------------------------------
// Fused: all weight transposes (idx < 12288) + ln1 (idx >= 12288).
// ---------------------------------------------------------------------------
__global__ __launch_bounds__(256) void transpose_ln(
        const float* __restrict__ Wq, const float* __restrict__ Wk,
        const float* __restrict__ Wv, const float* __restrict__ Wo,
        const float* __restrict__ W1, const float* __restrict__ W2,
        __bf16* __restrict__ WqkvT, __bf16* __restrict__ WoT,
        __bf16* __restrict__ W1T, __bf16* __restrict__ W2T,
        const float* __restrict__ x, const float* __restrict__ g1,
        const float* __restrict__ be1, __bf16* __restrict__ hb) {
    __shared__ float t[32][33];
    __shared__ float rs_[4], rss_[4];
    __shared__ float mu_s, inv_s;
    int idx = blockIdx.x;
    if (idx >= 12288) {
        int row = idx - 12288;
        const float4* xr = (const float4*)(x + (size_t)row * CC);
        float4 v = xr[threadIdx.x];
        float s  = v.x + v.y + v.z + v.w;
        float ss = v.x*v.x + v.y*v.y + v.z*v.z + v.w*v.w;
        #pragma unroll
        for (int off = 32; off; off >>= 1) {
            s  += __shfl_down(s, off);
            ss += __shfl_down(ss, off);
        }
        int lane = threadIdx.x & 63, wid = threadIdx.x >> 6;
        if (lane == 0) { rs_[wid] = s; rss_[wid] = ss; }
        __syncthreads();
        if (threadIdx.x == 0) {
            float S  = rs_[0] + rs_[1] + rs_[2] + rs_[3];
            float SS = rss_[0] + rss_[1] + rss_[2] + rss_[3];
            float mu  = S * (1.0f / CC);
            float var = SS * (1.0f / CC) - mu * mu;
            mu_s  = mu;
            inv_s = rsqrtf(var + LN_EPS);
        }
        __syncthreads();
        float mu = mu_s, inv = inv_s;
        float4 gv = ((const float4*)g1)[threadIdx.x];
        float4 bv = ((const float4*)be1)[threadIdx.x];
        bf16x4 o;
        o[0] = (__bf16)((v.x - mu) * inv * gv.x + bv.x);
        o[1] = (__bf16)((v.y - mu) * inv * gv.y + bv.y);
        o[2] = (__bf16)((v.z - mu) * inv * gv.z + bv.z);
        o[3] = (__bf16)((v.w - mu) * inv * gv.w + bv.w);
        *(bf16x4*)(hb + (size_t)row * CC + threadIdx.x * 4) = o;
        return;
    }
    const float* src; __bf16* dst; int K, N, tn, tk;
    if (idx < 3072) {
        int wsel = idx >> 10, local = idx & 1023;
        src = (wsel == 0) ? Wq : (wsel == 1 ? Wk : Wv);
        dst = WqkvT + (size_t)wsel * 1024 * 1024;
        K = 1024; N = 1024; tn = local & 31; tk = local >> 5;
    } else if (idx < 4096) {
        int local = idx - 3072;
        src = Wo; dst = WoT; K = 1024; N = 1024; tn = local & 31; tk = local >> 5;
    } else if (idx < 8192) {
        int local = idx - 4096;
        src = W1; dst = W1T; K = 1024; N = 4096; tn = local & 127; tk = local >> 7;
    } else {
        int local = idx - 8192;
        src = W2; dst = W2T; K = 4096; N = 1024; tn = local & 31; tk = local >> 5;
    }
    int n0 = tn * 32, k0 = tk * 32;
    int tx = threadIdx.x & 31, ty = threadIdx.x >> 5;
    #pragma unroll
    for (int r = ty; r < 32; r += 8)
        t[r][tx] = src[(size_t)(k0 + r) * N + n0 + tx];
    __syncthreads();
    #pragma unroll
    for (int r = ty; r < 32; r += 8)
        dst[(size_t)(n0 + r) * K + k0 + tx] = (__bf16)t[tx][r];
}

// ---------------------------------------------------------------------------
// Reduce 2 bf16 split-K partials + bias + residual -> x2 (fp32), then LN ->
// hb (bf16). Partials now cached (L2 hits); x streamed NT.
// ---------------------------------------------------------------------------
__global__ __launch_bounds__(256) void reduce_wo_ln(const __bf16* __restrict__ P,
                                                    const float* __restrict__ bo,
                                                    const float* __restrict__ x,
                                                    const float* __restrict__ g2,
                                                    const float* __restrict__ be2,
                                                    float* __restrict__ x2,
                                                    __bf16* __restrict__ hb) {
    int row = blockIdx.x;
    int c = threadIdx.x * 4;
    bf16x4 a0 = *(const bf16x4*)(P + (size_t)row * CC + c);
    bf16x4 a1 = *(const bf16x4*)(P + (size_t)BT * CC + (size_t)row * CC + c);
    float4 xb = __builtin_bit_cast(float4, nt_load128(x + (size_t)row * CC + c));
    float4 bb = *(const float4*)(bo + c);
    float4 v;
    v.x = xb.x + bb.x + (float)a0[0] + (float)a1[0];
    v.y = xb.y + bb.y + (float)a0[1] + (float)a1[1];
    v.z = xb.z + bb.z + (float)a0[2] + (float)a1[2];
    v.w = xb.w + bb.w + (float)a0[3] + (float)a1[3];
    *(float4*)(x2 + (size_t)row * CC + c) = v;   // cached: re-read by reduce_ffn

    float s  = v.x + v.y + v.z + v.w;
    float ss = v.x*v.x + v.y*v.y + v.z*v.z + v.w*v.w;
    #pragma unroll
    for (int off = 32; off; off >>= 1) {
        s  += __shfl_down(s, off);
        ss += __shfl_down(ss, off);
    }
    __shared__ float rs_[4], rss_[4];
    __shared__ float mu_s, inv_s;
    int lane = threadIdx.x & 63, wid = threadIdx.x >> 6;
    if (lane == 0) { rs_[wid] = s; rss_[wid] = ss; }
    __syncthreads();
    if (threadIdx.x == 0) {
        float S  = rs_[0] + rs_[1] + rs_[2] + rs_[3];
        float SS = rss_[0] + rss_[1] + rss_[2] + rss_[3];
        float mu  = S * (1.0f / CC);
        float var = SS * (1.0f / CC) - mu * mu;
        mu_s  = mu;
        inv_s = rsqrtf(var + LN_EPS);
    }
    __syncthreads();
    float mu = mu_s, inv = inv_s;
    float4 gv = ((const float4*)g2)[threadIdx.x];
    float4 bv = ((const float4*)be2)[threadIdx.x];
    bf16x4 o;
    o[0] = (__bf16)((v.x - mu) * inv * gv.x + bv.x);
    o[1] = (__bf16)((v.y - mu) * inv * gv.y + bv.y);
    o[2] = (__bf16)((v.z - mu) * inv * gv.z + bv.z);
    o[3] = (__bf16)((v.w - mu) * inv * gv.w + bv.w);
    *(bf16x4*)(hb + (size_t)row * CC + c) = o;
}

// ---------------------------------------------------------------------------
// Reduce 4 bf16 split-K partials + bias + residual(x2) -> out (fp32, NT).
// ---------------------------------------------------------------------------
__global__ __launch_bounds__(256) void reduce_ffn(const __bf16* __restrict__ P,
                                                  const float* __restrict__ b2,
                                                  const float* __restrict__ x2,
                                                  float* __restrict__ out) {
    int row = blockIdx.x;
    int c = threadIdx.x * 4;
    const size_t S = (size_t)BT * CC;
    float4 v = *(const float4*)(x2 + (size_t)row * CC + c);
    float4 bb = *(const float4*)(b2 + c);
    v.x += bb.x; v.y += bb.y; v.z += bb.z; v.w += bb.w;
    #pragma unroll
    for (int z = 0; z < 4; ++z) {
        bf16x4 a = *(const bf16x4*)(P + z * S + (size_t)row * CC + c);
        v.x += (float)a[0]; v.y += (float)a[1]; v.z += (float)a[2]; v.w += (float)a[3];
    }
    nt_store128(out + (size_t)row * CC + c, __builtin_bit_cast(uint32x4, v));
}

// ---------------------------------------------------------------------------
// bf16 MFMA GEMM v5: C[M,N] = A[M,K] @ Bt[N,K]^T.
// BK=64, XOR-swizzled LDS loads (r8), XCD chunking (r9), LDS-staged 16B
// coalesced epilogue (r10) with CACHED stores (r11: NT store tail-wait
// regressed — L2 completion + lazy writeback overlaps better).
// ---------------------------------------------------------------------------
template<int NT, int SK, typename OT, bool BIAS, bool RELU, bool RES,
         bool VSPLIT, bool STREAMC>
__global__ __launch_bounds__(256) void gemm_bf16(const __bf16* __restrict__ A,
                                                 const __bf16* __restrict__ Bt,
                                                 const float* __restrict__ bias,
                                                 const float* __restrict__ res,
                                                 OT* __restrict__ C,
                                                 __bf16* __restrict__ vt,
                                                 int M, int N, int K) {
    constexpr int JN = NT / 32;          // 4 or 2
    __shared__ __bf16 smem[128 * 64 + NT * 64];
    __bf16* As = smem;
    __bf16* Bs = smem + 128 * 64;
    int bx, by, bz;
    swizzle_xcd(bx, by, bz);
    const int tid = threadIdx.x;
    const int l = tid & 63, w = tid >> 6;
    const int m = l & 15, g = l >> 4;
    const int wm = w >> 1, wn = w & 1;
    const int m0 = by * 128, n0 = bx * NT;
    const int Keff = K / SK;
    const int kbase = (SK > 1) ? bz * Keff : 0;

    const int srow = l >> 3;
    const int sko  = ((l & 7) ^ ((l >> 3) & 7)) * 8;

    floatx4 acc[4][JN];
    #pragma unroll
    for (int i = 0; i < 4; ++i)
        #pragma unroll
        for (int j = 0; j < JN; ++j) {
            floatx4 z = {0.f, 0.f, 0.f, 0.f};
            acc[i][j] = z;
        }

    for (int kt = 0; kt < Keff; kt += 64) {
        __syncthreads();
        #pragma unroll
        for (int c = 0; c < 4; ++c) {
            int idx = w * 4 + c;
            gl_lds16(A + (size_t)(m0 + idx * 8 + srow) * K + kbase + kt + sko,
                     As + idx * 512);
        }
        #pragma unroll
        for (int c = 0; c < JN; ++c) {
            int idx = w * JN + c;
            gl_lds16(Bt + (size_t)(n0 + idx * 8 + srow) * K + kbase + kt + sko,
                     Bs + idx * 512);
        }
        __syncthreads();

        #pragma unroll
        for (int hf = 0; hf < 2; ++hf) {
            const int co = (((hf * 4 + g) ^ (m & 7)) * 8);
            bf16x8 af[4], bfr[JN];
            #pragma unroll
            for (int i = 0; i < 4; ++i)
                af[i] = *(const bf16x8*)&As[(wm * 64 + i * 16 + m) * 64 + co];
            #pragma unroll
            for (int j = 0; j < JN; ++j)
                bfr[j] = *(const bf16x8*)&Bs[(wn * (NT / 2) + j * 16 + m) * 64 + co];
            #pragma unroll
            for (int i = 0; i < 4; ++i)
                #pragma unroll
                for (int j = 0; j < JN; ++j)
                    acc[i][j] = MFMA32(af[i], bfr[j], acc[i][j]);
        }
    }

    if (SK > 1 || STREAMC) {
        // ---- LDS-staged coalesced cached epilogue (bf16 output) ----
        constexpr int CPR = NT / 8;     // 16B chunks per row
        __syncthreads();                // MFMA frag reads done; reuse smem
        #pragma unroll
        for (int i = 0; i < 4; ++i) {
            int lr0 = wm * 64 + i * 16 + g * 4;
            #pragma unroll
            for (int j = 0; j < JN; ++j) {
                int lcol = wn * (NT / 2) + j * 16 + m;
                int chunk = lcol >> 3, off = lcol & 7;
                float bv = BIAS ? bias[n0 + lcol] : 0.0f;
                #pragma unroll
                for (int r = 0; r < 4; ++r) {
                    float vo = acc[i][j][r] + bv;
                    if (RELU) vo = fmaxf(vo, 0.0f);
                    int lrow = lr0 + r;
                    smem[lrow * NT + ((chunk ^ (lrow & (CPR - 1))) * 8) + off] = (__bf16)vo;
                }
            }
        }
        __syncthreads();
        __bf16* base = (SK > 1) ? (__bf16*)C + (size_t)bz * M * N : (__bf16*)C;
        const int rpp = 256 / CPR;      // rows per pass
        #pragma unroll
        for (int ps = 0; ps < 128 / rpp; ++ps) {
            int lrow = ps * rpp + tid / CPR;
            int chunk = tid % CPR;
            int phys = chunk ^ (lrow & (CPR - 1));
            bf16x8 v = *(const bf16x8*)&smem[lrow * NT + phys * 8];
            *(uint32x4*)(base + (size_t)(m0 + lrow) * N + n0 + chunk * 8) =
                __builtin_bit_cast(uint32x4, v);
        }
    } else if (VSPLIT && n0 >= 2048) {
        // V columns transposed per-head into vt (cached: reused by attention)
        #pragma unroll
        for (int i = 0; i < 4; ++i) {
            int row = m0 + wm * 64 + i * 16 + g * 4;
            int bb = row >> 11, t0 = row & 2047;
            #pragma unroll
            for (int j = 0; j < JN; ++j) {
                int cv = n0 + wn * (NT / 2) + j * 16 + m - 2048;
                bf16x4 o;
                #pragma unroll
                for (int r = 0; r < 4; ++r) o[r] = (__bf16)acc[i][j][r];
                *(bf16x4*)(vt + ((size_t)(bb * NH + (cv >> 6)) * HD + (cv & 63)) * 2048 + t0) = o;
            }
        }
    } else {
        // cached epilogue (q|k of QKV, or fp32 outputs)
        #pragma unroll
        for (int i = 0; i < 4; ++i) {
            int row = m0 + wm * 64 + i * 16 + g * 4;
            #pragma unroll
            for (int j = 0; j < JN; ++j) {
                int col = n0 + wn * (NT / 2) + j * 16 + m;
                float bv = BIAS ? bias[col] : 0.0f;
                #pragma unroll
                for (int r = 0; r < 4; ++r) {
                    float vo = acc[i][j][r] + bv;
                    if (RELU) vo = fmaxf(vo, 0.0f);
                    if (RES)  vo += res[(size_t)(row + r) * N + col];
                    C[(size_t)(row + r) * N + col] = (OT)vo;
                }
            }
        }
    }
}

// ---------------------------------------------------------------------------
// Flash attention v3 (round 7): S^T orientation, makespan pairing,
// XOR-swizzled LDS, max-free softmax. Cached output store (read by Wo GEMM).
// ---------------------------------------------------------------------------
__global__ __launch_bounds__(256, 2) void attn_mfma3(const __bf16* __restrict__ qkv,
                                                     const __bf16* __restrict__ vt,
                                                     __bf16* __restrict__ att) {
    const int lin = blockIdx.x;
    const int half = lin >> 8, pid = lin & 255;
    const int q0 = pid & 7, h = (pid >> 3) & 15, b = pid >> 7;
    const int qt = half ? 15 - q0 : q0;

    const int tid = threadIdx.x;
    const int l = tid & 63, w = tid >> 6;
    const int m = l & 15, g = l >> 4;

    __shared__ __bf16 Ks[2][128][32];
    __shared__ __bf16 Vt3[8][64][16];

    const __bf16* qp = qkv + (size_t)b * TT * 3072 + h * HD;
    const __bf16* kp = qp + 1024;
    const __bf16* vh = vt + (size_t)(b * NH + h) * HD * 2048;

    bf16x8 qb[2][2];
    #pragma unroll
    for (int nt = 0; nt < 2; ++nt) {
        int qrow = qt * 128 + w * 32 + nt * 16 + m;
        qb[nt][0] = *(const bf16x8*)(qp + (size_t)qrow * 3072 + g * 8);
        qb[nt][1] = *(const bf16x8*)(qp + (size_t)qrow * 3072 + 32 + g * 8);
    }

    floatx4 O[2][4];
    float l_s[2] = {0.0f, 0.0f};
    #pragma unroll
    for (int nt = 0; nt < 2; ++nt)
        #pragma unroll
        for (int jd = 0; jd < 4; ++jd) {
            floatx4 z = {0.f, 0.f, 0.f, 0.f};
            O[nt][jd] = z;
        }

    for (int kt = 0; kt <= qt; ++kt) {
        __syncthreads();
        #pragma unroll
        for (int c = 0; c < 4; ++c) {
            int idx = w * 4 + c;
            int dh = idx >> 3, k16 = idx & 7;
            gl_lds16(kp + (size_t)(kt * 128 + k16 * 16 + (l >> 2)) * 3072
                        + dh * 32 + (((l & 3) ^ ((l >> 3) & 3)) * 8),
                     (__bf16*)Ks + dh * 4096 + k16 * 512);
        }
        #pragma unroll
        for (int c = 0; c < 4; ++c) {
            int idx = w * 4 + c;
            int jt = idx >> 1, dhf = idx & 1;
            gl_lds16(vh + (size_t)(dhf * 32 + (l >> 1)) * 2048 + kt * 128
                        + jt * 16 + (((l & 1) ^ ((l >> 3) & 1)) * 8),
                     (__bf16*)Vt3 + jt * 1024 + dhf * 512);
        }
        __syncthreads();

        floatx4 S[2][8];
        #pragma unroll
        for (int jt = 0; jt < 8; ++jt) {
            int co = (g ^ ((m >> 1) & 3)) * 8;
            bf16x8 kf0 = *(const bf16x8*)&Ks[0][jt * 16 + m][co];
            bf16x8 kf1 = *(const bf16x8*)&Ks[1][jt * 16 + m][co];
            #pragma unroll
            for (int nt = 0; nt < 2; ++nt) {
                floatx4 z = {0.f, 0.f, 0.f, 0.f};
                z = MFMA32(kf0, qb[nt][0], z);
                S[nt][jt] = MFMA32(kf1, qb[nt][1], z);
            }
        }

        bf16x4 pv[2][8];
        const bool last = (kt == qt);
        #pragma unroll
        for (int nt = 0; nt < 2; ++nt) {
            if (last) {
                int qr = w * 32 + nt * 16 + m;
                #pragma unroll
                for (int jt = 0; jt < 8; ++jt)
                    #pragma unroll
                    for (int r = 0; r < 4; ++r)
                        if (jt * 16 + g * 4 + r > qr) S[nt][jt][r] = -1e30f;
            }
            float ls = 0.0f;
            #pragma unroll
            for (int jt = 0; jt < 8; ++jt) {
                bf16x4 t;
                #pragma unroll
                for (int r = 0; r < 4; ++r) {
                    float p = __expf(S[nt][jt][r] * ATT_SCALE);
                    ls += p;
                    t[r] = (__bf16)p;
                }
                pv[nt][jt] = t;
            }
            l_s[nt] += ls;
        }

        #pragma unroll
        for (int jt = 0; jt < 8; ++jt)
            #pragma unroll
            for (int jd = 0; jd < 4; ++jd) {
                bf16x4 vf = *(const bf16x4*)&Vt3[jt][jd * 16 + m]
                                [((g >> 1) ^ ((m >> 2) & 1)) * 8 + (g & 1) * 4];
                #pragma unroll
                for (int nt = 0; nt < 2; ++nt)
                    O[nt][jd] = mfma16(vf, pv[nt][jt], O[nt][jd]);
            }
    }

    #pragma unroll
    for (int nt = 0; nt < 2; ++nt) {
        float lsum = l_s[nt];
        lsum += __shfl_xor(lsum, 16, 64);
        lsum += __shfl_xor(lsum, 32, 64);
        float inv = 1.0f / lsum;
        int qrow = qt * 128 + w * 32 + nt * 16 + m;
        #pragma unroll
        for (int jd = 0; jd < 4; ++jd) {
            bf16x4 o;
            #pragma unroll
            for (int r = 0; r < 4; ++r) o[r] = (__bf16)(O[nt][jd][r] * inv);
            *(bf16x4*)(att + ((size_t)b * TT + qrow) * CC + h * HD + jd * 16 + g * 4) = o;
        }
    }
}

// ---------------------------------------------------------------------------
extern "C" void kernel_launch(void* const* d_in, const int* in_sizes, int n_in,
                              void* d_out, int out_size, void* d_ws, size_t ws_size,
                              hipStream_t stream) {
    const float* x   = (const float*)d_in[0];
    const float* Wq  = (const float*)d_in[1];
    const float* Wk  = (const float*)d_in[2];
    const float* Wv  = (const float*)d_in[3];
    const float* Wo  = (const float*)d_in[4];
    const float* bo  = (const float*)d_in[5];
    const float* W1  = (const float*)d_in[6];
    const float* b1  = (const float*)d_in[7];
    const float* W2  = (const float*)d_in[8];
    const float* b2  = (const float*)d_in[9];
    const float* g1  = (const float*)d_in[10];
    const float* be1 = (const float*)d_in[11];
    const float* g2  = (const float*)d_in[12];
    const float* be2 = (const float*)d_in[13];
    float* out = (float*)d_out;

    char* p = (char*)d_ws;
    char*   pool  = p;          p += (size_t)32 * 1024 * 1024;
    __bf16* qkvb  = (__bf16*)pool;
    __bf16* vtb   = (__bf16*)(pool + (size_t)BT * 3072 * 2);
    __bf16* wop   = (__bf16*)pool;     // 2 x [BT][CC] bf16 partials
    __bf16* ffp   = (__bf16*)pool;     // 4 x [BT][CC] bf16 partials
    __bf16* attb  = (__bf16*)p; p += (size_t)BT * CC * 2;
    __bf16* hb    = (__bf16*)p; p += (size_t)BT * CC * 2;
    float*  x2    = (float*)p;  p += (size_t)BT * CC * 4;
    __bf16* ffb   = (__bf16*)p; p += (size_t)BT * 4096 * 2;
    __bf16* WqkvT = (__bf16*)p; p += (size_t)3072 * 1024 * 2;
    __bf16* WoT   = (__bf16*)p; p += (size_t)1024 * 1024 * 2;
    __bf16* W1T   = (__bf16*)p; p += (size_t)4096 * 1024 * 2;
    __bf16* W2T   = (__bf16*)p; p += (size_t)1024 * 4096 * 2;

    transpose_ln<<<16384, 256, 0, stream>>>(Wq, Wk, Wv, Wo, W1, W2,
                                            WqkvT, WoT, W1T, W2T,
                                            x, g1, be1, hb);
    // fused QKV projection; V written transposed into vtb (cached stores)
    gemm_bf16<128, 1, __bf16, false, false, false, true, false><<<dim3(24, 32), 256, 0, stream>>>(
        hb, WqkvT, nullptr, nullptr, qkvb, vtb, BT, 3072, 1024);
    attn_mfma3<<<512, 256, 0, stream>>>(qkvb, vtb, attb);
    // out proj: split-K=2 partials, LDS-staged coalesced cached stores
    gemm_bf16<64, 2, __bf16, false, false, false, false, false><<<dim3(16, 32, 2), 256, 0, stream>>>(
        attb, WoT, nullptr, nullptr, wop, nullptr, BT, 1024, 1024);
    reduce_wo_ln<<<BT, 256, 0, stream>>>(wop, bo, x, g2, be2, x2, hb);
    // ffn1 + bias + relu -> ffb, LDS-staged coalesced cached stores
    gemm_bf16<128, 1, __bf16, true, true, false, false, true><<<dim3(32, 32), 256, 0, stream>>>(
        hb, W1T, b1, nullptr, ffb, nullptr, BT, 4096, 1024);
    // ffn2: split-K=4 partials, LDS-staged coalesced cached stores
    gemm_bf16<128, 4, __bf16, false, false, false, false, false><<<dim3(8, 32, 4), 256, 0, stream>>>(
        ffb, W2T, nullptr, nullptr, ffp, nullptr, BT, 1024, 4096);
    reduce_ffn<<<BT, 256, 0, stream>>>(ffp, b2, x2, out);
}